// Round 1
// baseline (288.573 us; speedup 1.0000x reference)
//
#include <hip/hip_runtime.h>

#define B_   2
#define N_   16384
#define H_   8
#define GS_  256
#define NG_  64

typedef unsigned short u16;
typedef __attribute__((ext_vector_type(8))) short bf16x8;
typedef __attribute__((ext_vector_type(4))) float f32x4;
typedef __attribute__((ext_vector_type(8))) unsigned short us8;
typedef __attribute__((ext_vector_type(4))) unsigned short us4;
typedef __attribute__((ext_vector_type(4))) unsigned int u32x4;

__device__ __forceinline__ u16 f2b(float f){
  union { float f; unsigned u; } v; v.f = f;
  unsigned r = v.u + 0x7fffu + ((v.u >> 16) & 1u);
  return (u16)(r >> 16);
}

__device__ __forceinline__ void gload16(const void* g, const void* lds){
  __builtin_amdgcn_global_load_lds(
      (const __attribute__((address_space(1))) void*)g,
      (__attribute__((address_space(3))) void*)lds, 16, 0, 0);
}

__device__ __forceinline__ void stout(float* p, float v){ *p = v; }
__device__ __forceinline__ void stout(u16* p, float v){ *p = f2b(v); }

// ---------------- fp32 -> bf16 vector convert ----------------
__global__ void cvt_f32_bf16(const float4* __restrict__ in, us4* __restrict__ out, int n4){
  int i = blockIdx.x * 256 + threadIdx.x;
  if (i < n4){
    float4 v = in[i];
    us4 o;
    o[0] = f2b(v.x); o[1] = f2b(v.y); o[2] = f2b(v.z); o[3] = f2b(v.w);
    out[i] = o;
  }
}

// ---------------- weight convert + transpose: T[n][k] = bf16(W[k][n]) ----------------
__global__ void cvt_w_t(const float* __restrict__ W0, const float* __restrict__ W1,
                        const float* __restrict__ W2, const float* __restrict__ W3,
                        u16* __restrict__ T0, u16* __restrict__ T1,
                        u16* __restrict__ T2, u16* __restrict__ T3)
{
  int z = blockIdx.z;
  const float* W = (z==0)?W0:((z==1)?W1:((z==2)?W2:W3));
  u16* T = (z==0)?T0:((z==1)?T1:((z==2)?T2:T3));
  __shared__ float tile[16][17];
  int tx = threadIdx.x & 15, ty = threadIdx.x >> 4;
  int k0 = blockIdx.x*16, n0 = blockIdx.y*16;
  tile[ty][tx] = W[(k0+ty)*512 + n0 + tx];
  __syncthreads();
  T[(n0+ty)*512 + k0 + tx] = f2b(tile[tx][ty]);
}

// ---------------- bf16 GEMM: C[M][ldc] = A[M][512] @ Wt^T, Wt stored [outcol][k] ----------------
// MULTI: 12 col-tiles selecting Wq/Wk/Wv (q cols pre-scaled by 0.125)
template<typename OUT_T, bool MULTI>
__global__ __launch_bounds__(256, 2) void gemm_bf16k(
    const u16* __restrict__ A,
    const u16* __restrict__ Wt0, const u16* __restrict__ Wt1, const u16* __restrict__ Wt2,
    OUT_T* __restrict__ C, int ldc)
{
  __shared__ u16 Al[128*64];
  __shared__ u16 Bl[128*64];
  const int tid = threadIdx.x;
  const int l = tid & 63, w = tid >> 6;
  const int lr = l & 15, lg = l >> 4;
  const int bm = blockIdx.x, bn = blockIdx.y;
  const int wr = (w >> 1) * 64, wc = (w & 1) * 64;

  const u16* Wt; int ocolb; float qsc;
  if (MULTI){
    int wsel = bn >> 2;
    Wt = (wsel == 0) ? Wt0 : ((wsel == 1) ? Wt1 : Wt2);
    ocolb = (bn & 3) * 128;
    qsc = (wsel == 0) ? 0.125f : 1.0f;
  } else { Wt = Wt0; ocolb = bn * 128; qsc = 1.0f; }

  f32x4 acc[4][4];
#pragma unroll
  for (int m = 0; m < 4; ++m)
#pragma unroll
    for (int n = 0; n < 4; ++n) acc[m][n] = (f32x4){0.f,0.f,0.f,0.f};

  for (int kk = 0; kk < 512; kk += 64){
#pragma unroll
    for (int i = 0; i < 4; ++i){
      int o = i*4096 + tid*16;
      int row = o >> 7, c8 = (o & 127) >> 4;
      gload16(A  + (size_t)(bm*128 + row)*512 + kk + c8*8, (const char*)Al + i*4096 + w*1024);
      gload16(Wt + (size_t)(ocolb + row)*512 + kk + c8*8, (const char*)Bl + i*4096 + w*1024);
    }
    __syncthreads();
#pragma unroll
    for (int ks = 0; ks < 2; ++ks){
      bf16x8 af[4], bfv[4];
#pragma unroll
      for (int m = 0; m < 4; ++m) af[m]  = *(const bf16x8*)&Al[(wr + m*16 + lr)*64 + ks*32 + lg*8];
#pragma unroll
      for (int n = 0; n < 4; ++n) bfv[n] = *(const bf16x8*)&Bl[(wc + n*16 + lr)*64 + ks*32 + lg*8];
#pragma unroll
      for (int m = 0; m < 4; ++m)
#pragma unroll
        for (int n = 0; n < 4; ++n)
          acc[m][n] = __builtin_amdgcn_mfma_f32_16x16x32_bf16(af[m], bfv[n], acc[m][n], 0, 0, 0);
    }
    __syncthreads();
  }
#pragma unroll
  for (int m = 0; m < 4; ++m)
#pragma unroll
    for (int n = 0; n < 4; ++n)
#pragma unroll
      for (int j = 0; j < 4; ++j){
        int row = bm*128 + wr + m*16 + lg*4 + j;
        int col = bn*128 + wc + n*16 + lr;
        stout(&C[(size_t)row*ldc + col], acc[m][n][j] * qsc);
      }
}

// ---------------- fused local(512-window) + global(64) attention ----------------
// block = (g, h, b), 256 threads = 4 waves, wave w owns q-rows [w*64, w*64+64)
__global__ __launch_bounds__(256, 2) void attn_kernel(
    const u16* __restrict__ qkv,   // [B*N][1536] bf16 (q pre-scaled by 0.125)
    const int* __restrict__ idx,   // [B][N] permutation
    const u16* __restrict__ kgb,   // [H][64][64] bf16
    const u16* __restrict__ vgb,   // [H][64][64] bf16
    u16* __restrict__ outp)        // [B*N][512] bf16, scattered back to token order
{
  __shared__ u16 Qlds[256*64];   // 32KB; reused per-wave as P / out staging
  __shared__ u16 Kc[64*64];      // 8KB
  __shared__ u16 Vtc[64*64];     // 8KB, stored transposed [dv][t]

  const int tid = threadIdx.x;
  const int l = tid & 63, w = tid >> 6;
  const int lr = l & 15, lg = l >> 4;
  const int g = blockIdx.x, h = blockIdx.y, b = blockIdx.z;
  const int* __restrict__ idxB = idx + b * N_;

  // ---- stage Q (gathered rows) ----
#pragma unroll
  for (int i = 0; i < 8; ++i){
    int o = i*4096 + tid*16;
    int row = o >> 7, c8 = (o & 127) >> 4;
    int tok = idxB[g*GS_ + row];
    gload16(qkv + (size_t)(b*N_ + tok)*1536 + h*64 + c8*8, (const char*)Qlds + i*4096 + w*1024);
  }
  __syncthreads();

  bf16x8 qf[4][2];
#pragma unroll
  for (int m = 0; m < 4; ++m)
#pragma unroll
    for (int ks = 0; ks < 2; ++ks)
      qf[m][ks] = *(const bf16x8*)&Qlds[(w*64 + m*16 + lr)*64 + ks*32 + lg*8];

  u16* Pw = Qlds + w*4096;   // wave-private 64x64 bf16 region (same bytes this wave read Q from)

  f32x4 oacc[4][4];
  float mrun[4][4], lrun[4][4];
#pragma unroll
  for (int m = 0; m < 4; ++m)
#pragma unroll
    for (int n = 0; n < 4; ++n) oacc[m][n] = (f32x4){0.f,0.f,0.f,0.f};
#pragma unroll
  for (int m = 0; m < 4; ++m)
#pragma unroll
    for (int j = 0; j < 4; ++j){ mrun[m][j] = -1e30f; lrun[m][j] = 0.f; }

  // ---- local window: 8 chunks of 64 keys, online softmax ----
  for (int c = 0; c < 8; ++c){
    __syncthreads();
#pragma unroll
    for (int i = 0; i < 2; ++i){
      int o = i*4096 + tid*16;
      int row = o >> 7, c8 = (o & 127) >> 4;
      int p = g*GS_ + c*64 + row;
      int gi = (p < N_) ? p : (2*N_ - 1 - p);     // flipped-tail padding map
      int tok = idxB[gi];
      gload16(qkv + (size_t)(b*N_ + tok)*1536 + 512 + h*64 + c8*8, (const char*)Kc + i*4096 + w*1024);
    }
    {
      int pair = tid & 31, dvb = tid >> 5;
      int t0 = 2*pair;
      int p0 = g*GS_ + c*64 + t0;
      int p1 = p0 + 1;
      int tok0 = idxB[(p0 < N_) ? p0 : (2*N_ - 1 - p0)];
      int tok1 = idxB[(p1 < N_) ? p1 : (2*N_ - 1 - p1)];
      us8 v0 = *(const us8*)(qkv + (size_t)(b*N_ + tok0)*1536 + 1024 + h*64 + dvb*8);
      us8 v1 = *(const us8*)(qkv + (size_t)(b*N_ + tok1)*1536 + 1024 + h*64 + dvb*8);
      unsigned* V32 = (unsigned*)Vtc;
#pragma unroll
      for (int j = 0; j < 8; ++j)
        V32[(dvb*8 + j)*32 + pair] = (unsigned)v0[j] | ((unsigned)v1[j] << 16);
    }
    __syncthreads();

    f32x4 s[4][4];
#pragma unroll
    for (int m = 0; m < 4; ++m)
#pragma unroll
      for (int n = 0; n < 4; ++n) s[m][n] = (f32x4){0.f,0.f,0.f,0.f};
#pragma unroll
    for (int ks = 0; ks < 2; ++ks){
      bf16x8 kf[4];
#pragma unroll
      for (int n = 0; n < 4; ++n) kf[n] = *(const bf16x8*)&Kc[(n*16 + lr)*64 + ks*32 + lg*8];
#pragma unroll
      for (int m = 0; m < 4; ++m)
#pragma unroll
        for (int n = 0; n < 4; ++n)
          s[m][n] = __builtin_amdgcn_mfma_f32_16x16x32_bf16(qf[m][ks], kf[n], s[m][n], 0, 0, 0);
    }
    // online softmax update (row = m*16 + lg*4 + j, cols across lanes 0..15 of group + 4 n-frags)
#pragma unroll
    for (int m = 0; m < 4; ++m)
#pragma unroll
      for (int j = 0; j < 4; ++j){
        float cm = fmaxf(fmaxf(s[m][0][j], s[m][1][j]), fmaxf(s[m][2][j], s[m][3][j]));
        cm = fmaxf(cm, __shfl_xor(cm, 1));
        cm = fmaxf(cm, __shfl_xor(cm, 2));
        cm = fmaxf(cm, __shfl_xor(cm, 4));
        cm = fmaxf(cm, __shfl_xor(cm, 8));
        float mn = fmaxf(mrun[m][j], cm);
        float scl = __expf(mrun[m][j] - mn);
        mrun[m][j] = mn;
        float rs = 0.f;
#pragma unroll
        for (int n = 0; n < 4; ++n){
          float p = __expf(s[m][n][j] - mn);
          s[m][n][j] = p;
          rs += p;
        }
        rs += __shfl_xor(rs, 1);
        rs += __shfl_xor(rs, 2);
        rs += __shfl_xor(rs, 4);
        rs += __shfl_xor(rs, 8);
        lrun[m][j] = lrun[m][j]*scl + rs;
#pragma unroll
        for (int n = 0; n < 4; ++n) oacc[m][n][j] *= scl;
      }
    // P -> LDS (bf16, unnormalized)
#pragma unroll
    for (int m = 0; m < 4; ++m)
#pragma unroll
      for (int n = 0; n < 4; ++n)
#pragma unroll
        for (int j = 0; j < 4; ++j)
          Pw[(m*16 + lg*4 + j)*64 + n*16 + lr] = f2b(s[m][n][j]);
    __syncthreads();
    // PV
#pragma unroll
    for (int ks = 0; ks < 2; ++ks){
      bf16x8 pa[4], vb[4];
#pragma unroll
      for (int m = 0; m < 4; ++m) pa[m] = *(const bf16x8*)&Pw[(m*16 + lr)*64 + ks*32 + lg*8];
#pragma unroll
      for (int n = 0; n < 4; ++n) vb[n] = *(const bf16x8*)&Vtc[(n*16 + lr)*64 + ks*32 + lg*8];
#pragma unroll
      for (int m = 0; m < 4; ++m)
#pragma unroll
        for (int n = 0; n < 4; ++n)
          oacc[m][n] = __builtin_amdgcn_mfma_f32_16x16x32_bf16(pa[m], vb[n], oacc[m][n], 0, 0, 0);
    }
  }

  // finalize local softmax
#pragma unroll
  for (int m = 0; m < 4; ++m)
#pragma unroll
    for (int j = 0; j < 4; ++j){
      float inv = 1.f / lrun[m][j];
#pragma unroll
      for (int n = 0; n < 4; ++n) oacc[m][n][j] *= inv;
    }

  // ---- global attention (separate softmax over 64 global tokens) ----
  __syncthreads();
#pragma unroll
  for (int i = 0; i < 2; ++i){
    int o = i*4096 + tid*16;
    int row = o >> 7, c8 = (o & 127) >> 4;
    gload16(kgb + (size_t)(h*64 + row)*64 + c8*8, (const char*)Kc + i*4096 + w*1024);
  }
  {
    int pair = tid & 31, dvb = tid >> 5;
    int t0 = 2*pair;
    us8 v0 = *(const us8*)(vgb + (size_t)(h*64 + t0)*64 + dvb*8);
    us8 v1 = *(const us8*)(vgb + (size_t)(h*64 + t0 + 1)*64 + dvb*8);
    unsigned* V32 = (unsigned*)Vtc;
#pragma unroll
    for (int j = 0; j < 8; ++j)
      V32[(dvb*8 + j)*32 + pair] = (unsigned)v0[j] | ((unsigned)v1[j] << 16);
  }
  __syncthreads();

  f32x4 s2[4][4];
#pragma unroll
  for (int m = 0; m < 4; ++m)
#pragma unroll
    for (int n = 0; n < 4; ++n) s2[m][n] = (f32x4){0.f,0.f,0.f,0.f};
#pragma unroll
  for (int ks = 0; ks < 2; ++ks){
    bf16x8 kf[4];
#pragma unroll
    for (int n = 0; n < 4; ++n) kf[n] = *(const bf16x8*)&Kc[(n*16 + lr)*64 + ks*32 + lg*8];
#pragma unroll
    for (int m = 0; m < 4; ++m)
#pragma unroll
      for (int n = 0; n < 4; ++n)
        s2[m][n] = __builtin_amdgcn_mfma_f32_16x16x32_bf16(qf[m][ks], kf[n], s2[m][n], 0, 0, 0);
  }
  float l2s[4][4];
#pragma unroll
  for (int m = 0; m < 4; ++m)
#pragma unroll
    for (int j = 0; j < 4; ++j){
      float cm = fmaxf(fmaxf(s2[m][0][j], s2[m][1][j]), fmaxf(s2[m][2][j], s2[m][3][j]));
      cm = fmaxf(cm, __shfl_xor(cm, 1));
      cm = fmaxf(cm, __shfl_xor(cm, 2));
      cm = fmaxf(cm, __shfl_xor(cm, 4));
      cm = fmaxf(cm, __shfl_xor(cm, 8));
      float rs = 0.f;
#pragma unroll
      for (int n = 0; n < 4; ++n){
        float p = __expf(s2[m][n][j] - cm);
        s2[m][n][j] = p;
        rs += p;
      }
      rs += __shfl_xor(rs, 1);
      rs += __shfl_xor(rs, 2);
      rs += __shfl_xor(rs, 4);
      rs += __shfl_xor(rs, 8);
      l2s[m][j] = rs;
    }
#pragma unroll
  for (int m = 0; m < 4; ++m)
#pragma unroll
    for (int n = 0; n < 4; ++n)
#pragma unroll
      for (int j = 0; j < 4; ++j)
        Pw[(m*16 + lg*4 + j)*64 + n*16 + lr] = f2b(s2[m][n][j]);
  __syncthreads();

  f32x4 o2[4][4];
#pragma unroll
  for (int m = 0; m < 4; ++m)
#pragma unroll
    for (int n = 0; n < 4; ++n) o2[m][n] = (f32x4){0.f,0.f,0.f,0.f};
#pragma unroll
  for (int ks = 0; ks < 2; ++ks){
    bf16x8 pa[4], vb[4];
#pragma unroll
    for (int m = 0; m < 4; ++m) pa[m] = *(const bf16x8*)&Pw[(m*16 + lr)*64 + ks*32 + lg*8];
#pragma unroll
    for (int n = 0; n < 4; ++n) vb[n] = *(const bf16x8*)&Vtc[(n*16 + lr)*64 + ks*32 + lg*8];
#pragma unroll
    for (int m = 0; m < 4; ++m)
#pragma unroll
      for (int n = 0; n < 4; ++n)
        o2[m][n] = __builtin_amdgcn_mfma_f32_16x16x32_bf16(pa[m], vb[n], o2[m][n], 0, 0, 0);
  }
  __syncthreads();

  // combine, stage to LDS, coalesced scattered write
#pragma unroll
  for (int m = 0; m < 4; ++m)
#pragma unroll
    for (int n = 0; n < 4; ++n)
#pragma unroll
      for (int j = 0; j < 4; ++j){
        float v = oacc[m][n][j] + o2[m][n][j] / l2s[m][j];
        Pw[(m*16 + lg*4 + j)*64 + n*16 + lr] = f2b(v);
      }
  __syncthreads();
#pragma unroll
  for (int i8 = 0; i8 < 8; ++i8){
    int o = i8*1024 + l*16;
    int row = o >> 7, c8 = (o & 127) >> 4;
    int tok = idxB[g*GS_ + w*64 + row];
    *(u32x4*)(outp + (size_t)(b*N_ + tok)*512 + h*64 + c8*8) = *(const u32x4*)((const char*)Pw + o);
  }
}

extern "C" void kernel_launch(void* const* d_in, const int* in_sizes, int n_in,
                              void* d_out, int out_size, void* d_ws, size_t ws_size,
                              hipStream_t stream)
{
  const float* x  = (const float*)d_in[0];
  const int*  idx = (const int*)d_in[1];
  const float* kg = (const float*)d_in[2];
  const float* vg = (const float*)d_in[3];
  const float* Wq = (const float*)d_in[4];
  const float* Wk = (const float*)d_in[5];
  const float* Wv = (const float*)d_in[6];
  const float* Wp = (const float*)d_in[7];
  float* out = (float*)d_out;

  char* ws = (char*)d_ws;
  u16* Xb   = (u16*)ws;                                   // 33,554,432 B (reused as attn_o)
  u16* qkv  = (u16*)(ws + 33554432);                      // 100,663,296 B
  u16* Wqt  = (u16*)(ws + 134217728);
  u16* Wkt  = (u16*)(ws + 134217728 + 524288);
  u16* Wvt  = (u16*)(ws + 134217728 + 2*524288);
  u16* Wpt  = (u16*)(ws + 134217728 + 3*524288);
  u16* kgb  = (u16*)(ws + 134217728 + 4*524288);
  u16* vgb  = (u16*)(ws + 134217728 + 4*524288 + 65536);
  u16* attn_o = Xb;  // safe: gemm_qkv (reads Xb) completes before attn writes

  cvt_f32_bf16<<<16384, 256, 0, stream>>>((const float4*)x, (us4*)Xb, 16777216/4);
  cvt_f32_bf16<<<32, 256, 0, stream>>>((const float4*)kg, (us4*)kgb, 32768/4);
  cvt_f32_bf16<<<32, 256, 0, stream>>>((const float4*)vg, (us4*)vgb, 32768/4);
  cvt_w_t<<<dim3(32,32,4), 256, 0, stream>>>(Wq, Wk, Wv, Wp, Wqt, Wkt, Wvt, Wpt);
  gemm_bf16k<u16, true><<<dim3(256,12), 256, 0, stream>>>(Xb, Wqt, Wkt, Wvt, qkv, 1536);
  attn_kernel<<<dim3(64,8,2), 256, 0, stream>>>(qkv, idx, kgb, vgb, attn_o);
  gemm_bf16k<float, false><<<dim3(256,4), 256, 0, stream>>>(attn_o, Wpt, Wpt, Wpt, out, 512);
}